// Round 19
// baseline (64.335 us; speedup 1.0000x reference)
//
#include <hip/hip_runtime.h>
#include <hip/hip_bf16.h>

typedef __bf16 bf16_t;
typedef __bf16 bf16x8 __attribute__((ext_vector_type(8)));
typedef float  f32x4  __attribute__((ext_vector_type(4)));

#define M_ROWS 12544   // 64*14*14
#define K_DIM  512
#define N_DIM  2048
#define BM 256
#define BN 128
#define BK 32
#define KSTEPS (K_DIM / BK)        // 16
#define TILES_M (M_ROWS / BM)      // 49
#define TILES_N (N_DIM / BN)       // 16
#define NBLK (TILES_M * TILES_N)   // 784 (divisible by 8)
#define LN_BLOCKS (M_ROWS / 4)     // 3136
#define WT_BLOCKS ((K_DIM / 32) * (N_DIM / 32))   // 1024

// ------------- Kernel 1: fused {residual add + LayerNorm} | {W transpose} ---
__global__ __launch_bounds__(256) void prep(
    const float* __restrict__ xa, const float* __restrict__ xb,
    const float* __restrict__ gamma, const float* __restrict__ beta,
    const float* __restrict__ W,
    bf16_t* __restrict__ xn, bf16_t* __restrict__ Wt)
{
    __shared__ float t[32][33];
    if (blockIdx.x < LN_BLOCKS) {
        const int wave = threadIdx.x >> 6;
        const int lane = threadIdx.x & 63;
        const int row  = blockIdx.x * 4 + wave;
        const size_t base = (size_t)row * K_DIM + lane * 8;

        float4 a0 = *(const float4*)(xa + base);
        float4 a1 = *(const float4*)(xa + base + 4);
        float4 b0 = *(const float4*)(xb + base);
        float4 b1 = *(const float4*)(xb + base + 4);

        float v[8] = {a0.x + b0.x, a0.y + b0.y, a0.z + b0.z, a0.w + b0.w,
                      a1.x + b1.x, a1.y + b1.y, a1.z + b1.z, a1.w + b1.w};
        float s = 0.f, sq = 0.f;
#pragma unroll
        for (int j = 0; j < 8; ++j) { s += v[j]; sq += v[j] * v[j]; }
#pragma unroll
        for (int off = 32; off >= 1; off >>= 1) {
            s  += __shfl_xor(s, off, 64);
            sq += __shfl_xor(sq, off, 64);
        }
        const float mean = s * (1.0f / 512.0f);
        const float var  = sq * (1.0f / 512.0f) - mean * mean;
        const float rstd = rsqrtf(var + 1e-5f);

        float4 g0  = *(const float4*)(gamma + lane * 8);
        float4 g1  = *(const float4*)(gamma + lane * 8 + 4);
        float4 be0 = *(const float4*)(beta  + lane * 8);
        float4 be1 = *(const float4*)(beta  + lane * 8 + 4);
        float g[8]  = {g0.x, g0.y, g0.z, g0.w, g1.x, g1.y, g1.z, g1.w};
        float bt[8] = {be0.x, be0.y, be0.z, be0.w, be1.x, be1.y, be1.z, be1.w};

        bf16x8 o;
#pragma unroll
        for (int j = 0; j < 8; ++j)
            o[j] = (bf16_t)((v[j] - mean) * rstd * g[j] + bt[j]);
        *(bf16x8*)(xn + base) = o;
    } else {
        const int b  = blockIdx.x - LN_BLOCKS;
        const int bk = b & 15;
        const int bn = b >> 4;
        const int tx = threadIdx.x & 31;
        const int ty = threadIdx.x >> 5;
#pragma unroll
        for (int r = 0; r < 4; ++r) {
            int k = bk * 32 + ty + r * 8;
            t[ty + r * 8][tx] = W[(size_t)k * N_DIM + bn * 32 + tx];
        }
        __syncthreads();
#pragma unroll
        for (int r = 0; r < 4; ++r) {
            int n = bn * 32 + ty + r * 8;
            Wt[(size_t)n * K_DIM + bk * 32 + tx] = (bf16_t)t[tx][ty + r * 8];
        }
    }
}

// ---------------- Kernel 2: bf16 MFMA GEMM + bias + exact GELU --------------
__device__ __forceinline__ void gload_lds16(const bf16_t* g, bf16_t* l) {
    __builtin_amdgcn_global_load_lds(
        (const __attribute__((address_space(1))) void*)g,
        (__attribute__((address_space(3))) void*)l, 16, 0, 0);
}

// Branchless exact-GELU: erf via Abramowitz-Stegun 7.1.26 (|err| < ~2e-7)
__device__ __forceinline__ float gelu_f(float x) {
    const float y = fabsf(x) * 0.70710678118654752f;
    const float t = __builtin_amdgcn_rcpf(__builtin_fmaf(0.3275911f, y, 1.0f));
    float p = __builtin_fmaf(1.061405429f, t, -1.453152027f);
    p = __builtin_fmaf(p, t, 1.421413741f);
    p = __builtin_fmaf(p, t, -0.284496736f);
    p = __builtin_fmaf(p, t, 0.254829592f);
    p = p * t;
    const float e = __expf(-y * y);
    float er = __builtin_fmaf(-p, e, 1.0f);   // erf(|x|/sqrt2)
    er = __builtin_copysignf(er, x);
    return 0.5f * x * (1.0f + er);
}

// BM=256 x BN=128, BK=32, 4 waves of 128x64 output each (8x4 fragments):
// fragment reuse 32 MFMA / 12 b128 reads (2.67x vs 2x at 4x4) -> total
// LDS reads 784 -> 588 MB (-25%), and each barrier-pair covers 32 MFMA
// (2x amortization of per-step sync cost, half the blocks). Everything
// else proven: R5 BK=32 both-sides swizzle, counted vmcnt(6) gate, R14
// LDS-transpose NT epilogue. 48 KB LDS dbuf, launch_bounds(256,2)
// (VGPR ~210 < 256, no spill), grid 784 (%8==0, XCD-bijective, tn-fast).
__global__ __launch_bounds__(256, 2) void gemm_bias_gelu(
    const bf16_t* __restrict__ A,   // [M_ROWS][K_DIM] bf16
    const bf16_t* __restrict__ Bt,  // [N_DIM][K_DIM]  bf16 (W^T)
    const float* __restrict__ bias, // [N_DIM]
    float* __restrict__ out)        // [M_ROWS][N_DIM] f32
{
    // unified 48 KB LDS: As dbuf 2x16KB | Bs dbuf 2x8KB; epilogue overlays
    __shared__ bf16_t smem[24576];
    bf16_t* As[2] = { smem,         smem + 8192  };
    bf16_t* Bs[2] = { smem + 16384, smem + 20480 };

    const int bid = blockIdx.x;
    const int wg  = (bid & 7) * (NBLK / 8) + (bid >> 3);  // XCD-chunked, bijective
    const int tm  = wg >> 4;            // 0..48
    const int tn  = wg & 15;            // tn-fast: B stripe stays L2-hot

    const int tid  = threadIdx.x;
    const int wave = tid >> 6;
    const int lane = tid & 63;
    const int wr = wave >> 1;           // A half (128 rows)
    const int wc = wave & 1;            // B half (64 cols)

    const bf16_t* Ab = A  + (size_t)tm * BM * K_DIM;
    const bf16_t* Bb = Bt + (size_t)tn * BN * K_DIM;

    // staging: seg = 16 rows x 32 k = 1024 B = 64 lanes x 16 B
    const int srow = lane >> 2;                       // row within segment
    const int gsrc = (lane & 3) ^ ((lane >> 3) & 3);  // inverse-swizzled chunk

    f32x4 acc[8][4];
#pragma unroll
    for (int m = 0; m < 8; ++m)
#pragma unroll
        for (int n = 0; n < 4; ++n)
            acc[m][n] = (f32x4){0.f, 0.f, 0.f, 0.f};

    auto stage = [&](int buf, int k0) {
#pragma unroll
        for (int c = 0; c < 4; ++c) {                 // A: 16 segs, 4/wave
            const int seg = wave * 4 + c;
            const int row = seg * 16 + srow;
            gload_lds16(Ab + (size_t)row * K_DIM + k0 + gsrc * 8, As[buf] + seg * 512);
        }
#pragma unroll
        for (int c = 0; c < 2; ++c) {                 // B: 8 segs, 2/wave
            const int seg = wave * 2 + c;
            const int row = seg * 16 + srow;
            gload_lds16(Bb + (size_t)row * K_DIM + k0 + gsrc * 8, Bs[buf] + seg * 512);
        }
    };

    stage(0, 0);   // prologue: 6 loads in flight

#pragma unroll
    for (int t = 0; t < KSTEPS; ++t) {
        const int cur = t & 1;
        if (t < KSTEPS - 1) {
            stage(cur ^ 1, (t + 1) * BK);                    // +6 loads (next tile)
            asm volatile("s_waitcnt vmcnt(6)" ::: "memory"); // tile t landed
        } else {
            asm volatile("s_waitcnt vmcnt(0)" ::: "memory");
        }
        __builtin_amdgcn_s_barrier();

        bf16x8 af[8], bfr[4];
        const int j = lane >> 4;                      // 16B k-chunk 0..3
#pragma unroll
        for (int m = 0; m < 8; ++m) {
            const int r = wr * 128 + m * 16 + (lane & 15);   // 0..255
            af[m] = *(const bf16x8*)(&As[cur][r * BK + ((j ^ ((r >> 1) & 3)) << 3)]);
        }
#pragma unroll
        for (int n = 0; n < 4; ++n) {
            const int r = wc * 64 + n * 16 + (lane & 15);    // 0..127
            bfr[n] = *(const bf16x8*)(&Bs[cur][r * BK + ((j ^ ((r >> 1) & 3)) << 3)]);
        }
        __builtin_amdgcn_s_setprio(1);
#pragma unroll
        for (int m = 0; m < 8; ++m)
#pragma unroll
            for (int n = 0; n < 4; ++n)
                acc[m][n] = __builtin_amdgcn_mfma_f32_16x16x32_bf16(
                    af[m], bfr[n], acc[m][n], 0, 0, 0);
        __builtin_amdgcn_s_setprio(0);

        if (t < KSTEPS - 1) __builtin_amdgcn_s_barrier();  // reads done before restage
    }

    // ---- Epilogue: bias + exact GELU, LDS-transpose -> coalesced NT dwordx4.
    // acc C/D layout: col = lane&15, row = (lane>>4)*4 + reg (m89/m91).
    __syncthreads();   // all waves done with staging-LDS fragment reads
    float* sco = ((float*)smem) + wave * (16 * 68 + 16);   // 4 x 4416 B <= 17.7 KB

    const int l15 = lane & 15;
    const int rbase = tm * BM + wr * 128;
    const int cbase = tn * BN + wc * 64;

    float bv[4];
#pragma unroll
    for (int n = 0; n < 4; ++n) bv[n] = bias[cbase + n * 16 + l15];

#pragma unroll
    for (int m = 0; m < 8; ++m) {
        // write phase: 16 scalar ds_writes (2-way bank alias = free)
#pragma unroll
        for (int n = 0; n < 4; ++n) {
#pragma unroll
            for (int i = 0; i < 4; ++i) {
                const int row = (lane >> 4) * 4 + i;         // 0..15
                sco[row * 68 + n * 16 + l15] = gelu_f(acc[m][n][i] + bv[n]);
            }
        }
        asm volatile("s_waitcnt lgkmcnt(0)" ::: "memory");
        __builtin_amdgcn_sched_barrier(0);

        // read+store phase: 4 wide NT stores, each 4 rows x 256 B contiguous
#pragma unroll
        for (int jj = 0; jj < 4; ++jj) {
            const int row = jj * 4 + (lane >> 4);            // 0..15
            const f32x4 v = *(const f32x4*)&sco[row * 68 + l15 * 4];
            __builtin_nontemporal_store(v,
                (f32x4*)(out + (size_t)(rbase + m * 16 + row) * N_DIM
                             + cbase + l15 * 4));
        }
        asm volatile("s_waitcnt lgkmcnt(0)" ::: "memory");
        __builtin_amdgcn_sched_barrier(0);
    }
}

extern "C" void kernel_launch(void* const* d_in, const int* in_sizes, int n_in,
                              void* d_out, int out_size, void* d_ws, size_t ws_size,
                              hipStream_t stream)
{
    const float* x203  = (const float*)d_in[0];
    const float* x217  = (const float*)d_in[1];
    const float* gamma = (const float*)d_in[2];
    const float* beta  = (const float*)d_in[3];
    const float* W     = (const float*)d_in[4];
    const float* bias  = (const float*)d_in[5];
    float* out = (float*)d_out;

    bf16_t* xn = (bf16_t*)d_ws;
    bf16_t* Wt = (bf16_t*)((char*)d_ws + (size_t)M_ROWS * K_DIM * sizeof(bf16_t));

    prep<<<LN_BLOCKS + WT_BLOCKS, 256, 0, stream>>>(x203, x217, gamma, beta, W, xn, Wt);
    gemm_bias_gelu<<<NBLK, 256, 0, stream>>>(xn, Wt, bias, out);
}

// Round 20
// 57.114 us; speedup vs baseline: 1.1264x; 1.1264x over previous
//
#include <hip/hip_runtime.h>
#include <hip/hip_bf16.h>

typedef __bf16 bf16_t;
typedef __bf16 bf16x8 __attribute__((ext_vector_type(8)));
typedef float  f32x4  __attribute__((ext_vector_type(4)));

#define M_ROWS 12544   // 64*14*14
#define K_DIM  512
#define N_DIM  2048
#define BM 128
#define BN 128
#define BK 32
#define KSTEPS (K_DIM / BK)        // 16
#define TILES_M (M_ROWS / BM)      // 98
#define TILES_N (N_DIM / BN)       // 16
#define NBLK (TILES_M * TILES_N)   // 1568 (divisible by 8)
#define LN_BLOCKS (M_ROWS / 4)     // 3136
#define WT_BLOCKS ((K_DIM / 32) * (N_DIM / 32))   // 1024

// ------------- Kernel 1: fused {residual add + LayerNorm} | {W transpose} ---
__global__ __launch_bounds__(256) void prep(
    const float* __restrict__ xa, const float* __restrict__ xb,
    const float* __restrict__ gamma, const float* __restrict__ beta,
    const float* __restrict__ W,
    bf16_t* __restrict__ xn, bf16_t* __restrict__ Wt)
{
    __shared__ float t[32][33];
    if (blockIdx.x < LN_BLOCKS) {
        const int wave = threadIdx.x >> 6;
        const int lane = threadIdx.x & 63;
        const int row  = blockIdx.x * 4 + wave;
        const size_t base = (size_t)row * K_DIM + lane * 8;

        float4 a0 = *(const float4*)(xa + base);
        float4 a1 = *(const float4*)(xa + base + 4);
        float4 b0 = *(const float4*)(xb + base);
        float4 b1 = *(const float4*)(xb + base + 4);

        float v[8] = {a0.x + b0.x, a0.y + b0.y, a0.z + b0.z, a0.w + b0.w,
                      a1.x + b1.x, a1.y + b1.y, a1.z + b1.z, a1.w + b1.w};
        float s = 0.f, sq = 0.f;
#pragma unroll
        for (int j = 0; j < 8; ++j) { s += v[j]; sq += v[j] * v[j]; }
#pragma unroll
        for (int off = 32; off >= 1; off >>= 1) {
            s  += __shfl_xor(s, off, 64);
            sq += __shfl_xor(sq, off, 64);
        }
        const float mean = s * (1.0f / 512.0f);
        const float var  = sq * (1.0f / 512.0f) - mean * mean;
        const float rstd = rsqrtf(var + 1e-5f);

        float4 g0  = *(const float4*)(gamma + lane * 8);
        float4 g1  = *(const float4*)(gamma + lane * 8 + 4);
        float4 be0 = *(const float4*)(beta  + lane * 8);
        float4 be1 = *(const float4*)(beta  + lane * 8 + 4);
        float g[8]  = {g0.x, g0.y, g0.z, g0.w, g1.x, g1.y, g1.z, g1.w};
        float bt[8] = {be0.x, be0.y, be0.z, be0.w, be1.x, be1.y, be1.z, be1.w};

        bf16x8 o;
#pragma unroll
        for (int j = 0; j < 8; ++j)
            o[j] = (bf16_t)((v[j] - mean) * rstd * g[j] + bt[j]);
        *(bf16x8*)(xn + base) = o;
    } else {
        const int b  = blockIdx.x - LN_BLOCKS;
        const int bk = b & 15;
        const int bn = b >> 4;
        const int tx = threadIdx.x & 31;
        const int ty = threadIdx.x >> 5;
#pragma unroll
        for (int r = 0; r < 4; ++r) {
            int k = bk * 32 + ty + r * 8;
            t[ty + r * 8][tx] = W[(size_t)k * N_DIM + bn * 32 + tx];
        }
        __syncthreads();
#pragma unroll
        for (int r = 0; r < 4; ++r) {
            int n = bn * 32 + ty + r * 8;
            Wt[(size_t)n * K_DIM + bk * 32 + tx] = (bf16_t)t[tx][ty + r * 8];
        }
    }
}

// ---------------- Kernel 2: bf16 MFMA GEMM + bias + exact GELU --------------
__device__ __forceinline__ void gload_lds16(const bf16_t* g, bf16_t* l) {
    __builtin_amdgcn_global_load_lds(
        (const __attribute__((address_space(1))) void*)g,
        (__attribute__((address_space(3))) void*)l, 16, 0, 0);
}

// Branchless exact-GELU: erf via Abramowitz-Stegun 7.1.26 (|err| < ~2e-7)
__device__ __forceinline__ float gelu_f(float x) {
    const float y = fabsf(x) * 0.70710678118654752f;
    const float t = __builtin_amdgcn_rcpf(__builtin_fmaf(0.3275911f, y, 1.0f));
    float p = __builtin_fmaf(1.061405429f, t, -1.453152027f);
    p = __builtin_fmaf(p, t, 1.421413741f);
    p = __builtin_fmaf(p, t, -0.284496736f);
    p = __builtin_fmaf(p, t, 0.254829592f);
    p = p * t;
    const float e = __expf(-y * y);
    float er = __builtin_fmaf(-p, e, 1.0f);   // erf(|x|/sqrt2)
    er = __builtin_copysignf(er, x);
    return 0.5f * x * (1.0f + er);
}

// BEST CONFIG (R17, 59.7 us): R5-proven K-loop (BK=32, dbuf 32 KB LDS,
// vmcnt(4) counted gate, both-sides XOR swizzle) + R14-proven LDS-transpose
// NT epilogue + 4 blocks/CU (__launch_bounds__(256,4)): 16 fine-grained
// rounds-free waves/CU; each block's store-bound epilogue hides under 3
// co-resident K-loops. R18's bigger wave-tile (2 blocks/CU) regressed —
// occupancy beats LDS-read reduction at this shape.
__global__ __launch_bounds__(256, 4) void gemm_bias_gelu(
    const bf16_t* __restrict__ A,   // [M_ROWS][K_DIM] bf16
    const bf16_t* __restrict__ Bt,  // [N_DIM][K_DIM]  bf16 (W^T)
    const float* __restrict__ bias, // [N_DIM]
    float* __restrict__ out)        // [M_ROWS][N_DIM] f32
{
    // unified 32 KB LDS: staging (As 2x8KB | Bs 2x8KB) then epilogue scratch
    __shared__ bf16_t smem[16384];
    bf16_t* As[2] = { smem,        smem + 4096 };
    bf16_t* Bs[2] = { smem + 8192, smem + 12288 };

    const int bid = blockIdx.x;
    const int wg  = (bid & 7) * (NBLK / 8) + (bid >> 3);  // XCD-chunked, bijective
    const int tm  = wg >> 4;
    const int tn  = wg & 15;            // tn-fast: B stripe stays L2-hot

    const int tid  = threadIdx.x;
    const int wave = tid >> 6;
    const int lane = tid & 63;
    const int wr = wave >> 1;
    const int wc = wave & 1;

    const bf16_t* Ab = A  + (size_t)tm * BM * K_DIM;
    const bf16_t* Bb = Bt + (size_t)tn * BN * K_DIM;

    // staging: seg = 16 rows x 32 k = 1024 B = 64 lanes x 16 B
    const int srow = lane >> 2;                       // row within segment
    const int gsrc = (lane & 3) ^ ((lane >> 3) & 3);  // inverse-swizzled chunk

    f32x4 acc[4][4];
#pragma unroll
    for (int m = 0; m < 4; ++m)
#pragma unroll
        for (int n = 0; n < 4; ++n)
            acc[m][n] = (f32x4){0.f, 0.f, 0.f, 0.f};

    auto stage = [&](int buf, int k0) {
#pragma unroll
        for (int c = 0; c < 2; ++c) {
            const int seg = wave * 2 + c;             // 0..7, wave-uniform
            const int row = seg * 16 + srow;
            gload_lds16(Ab + (size_t)row * K_DIM + k0 + gsrc * 8, As[buf] + seg * 512);
            gload_lds16(Bb + (size_t)row * K_DIM + k0 + gsrc * 8, Bs[buf] + seg * 512);
        }
    };

    stage(0, 0);   // prologue: 4 loads in flight

#pragma unroll
    for (int t = 0; t < KSTEPS; ++t) {
        const int cur = t & 1;
        if (t < KSTEPS - 1) {
            stage(cur ^ 1, (t + 1) * BK);                    // +4 loads (next tile)
            asm volatile("s_waitcnt vmcnt(4)" ::: "memory"); // tile t landed
        } else {
            asm volatile("s_waitcnt vmcnt(0)" ::: "memory");
        }
        __builtin_amdgcn_s_barrier();

        bf16x8 af[4], bfr[4];
        const int j = lane >> 4;                      // 16B k-chunk 0..3
#pragma unroll
        for (int m = 0; m < 4; ++m) {
            const int r = wr * 64 + m * 16 + (lane & 15);
            af[m] = *(const bf16x8*)(&As[cur][r * BK + ((j ^ ((r >> 1) & 3)) << 3)]);
        }
#pragma unroll
        for (int n = 0; n < 4; ++n) {
            const int r = wc * 64 + n * 16 + (lane & 15);
            bfr[n] = *(const bf16x8*)(&Bs[cur][r * BK + ((j ^ ((r >> 1) & 3)) << 3)]);
        }
        __builtin_amdgcn_s_setprio(1);
#pragma unroll
        for (int m = 0; m < 4; ++m)
#pragma unroll
            for (int n = 0; n < 4; ++n)
                acc[m][n] = __builtin_amdgcn_mfma_f32_16x16x32_bf16(
                    af[m], bfr[n], acc[m][n], 0, 0, 0);
        __builtin_amdgcn_s_setprio(0);

        if (t < KSTEPS - 1) __builtin_amdgcn_s_barrier();  // reads done before restage
    }

    // ---- Epilogue: bias + exact GELU, LDS-transpose -> coalesced NT dwordx4.
    // acc C/D layout: col = lane&15, row = (lane>>4)*4 + reg (m89/m91).
    __syncthreads();   // all waves done with staging-LDS fragment reads
    float* sco = ((float*)smem) + wave * (16 * 68 + 16);   // 4 x 4416 B <= 17.7 KB

    const int l15 = lane & 15;
    const int rbase = tm * BM + wr * 64;
    const int cbase = tn * BN + wc * 64;

    float bv[4];
#pragma unroll
    for (int n = 0; n < 4; ++n) bv[n] = bias[cbase + n * 16 + l15];

#pragma unroll
    for (int m = 0; m < 4; ++m) {
        // write phase: 16 scalar ds_writes (2-way bank alias = free)
#pragma unroll
        for (int n = 0; n < 4; ++n) {
#pragma unroll
            for (int i = 0; i < 4; ++i) {
                const int row = (lane >> 4) * 4 + i;         // 0..15
                sco[row * 68 + n * 16 + l15] = gelu_f(acc[m][n][i] + bv[n]);
            }
        }
        asm volatile("s_waitcnt lgkmcnt(0)" ::: "memory");
        __builtin_amdgcn_sched_barrier(0);

        // read+store phase: 4 wide NT stores, each 4 rows x 256 B contiguous
#pragma unroll
        for (int jj = 0; jj < 4; ++jj) {
            const int row = jj * 4 + (lane >> 4);            // 0..15
            const f32x4 v = *(const f32x4*)&sco[row * 68 + l15 * 4];
            __builtin_nontemporal_store(v,
                (f32x4*)(out + (size_t)(rbase + m * 16 + row) * N_DIM
                             + cbase + l15 * 4));
        }
        asm volatile("s_waitcnt lgkmcnt(0)" ::: "memory");
        __builtin_amdgcn_sched_barrier(0);
    }
}

extern "C" void kernel_launch(void* const* d_in, const int* in_sizes, int n_in,
                              void* d_out, int out_size, void* d_ws, size_t ws_size,
                              hipStream_t stream)
{
    const float* x203  = (const float*)d_in[0];
    const float* x217  = (const float*)d_in[1];
    const float* gamma = (const float*)d_in[2];
    const float* beta  = (const float*)d_in[3];
    const float* W     = (const float*)d_in[4];
    const float* bias  = (const float*)d_in[5];
    float* out = (float*)d_out;

    bf16_t* xn = (bf16_t*)d_ws;
    bf16_t* Wt = (bf16_t*)((char*)d_ws + (size_t)M_ROWS * K_DIM * sizeof(bf16_t));

    prep<<<LN_BLOCKS + WT_BLOCKS, 256, 0, stream>>>(x203, x217, gamma, beta, W, xn, Wt);
    gemm_bias_gelu<<<NBLK, 256, 0, stream>>>(xn, Wt, bias, out);
}